// Round 5
// baseline (42.066 us; speedup 1.0000x reference)
//
#include <hip/hip_runtime.h>
#include <hip/hip_bf16.h>
#include <math.h>

typedef __attribute__((ext_vector_type(8))) short short8;
typedef __attribute__((ext_vector_type(4))) float floatx4;

// ---- workspace byte offsets (ws is ~256 MB, poisoned 0xAA once; we overwrite all we read) ----
#define WS_WREDT 0u           // 8192 f32 (32 KB)
#define WS_WMA   (1u << 20)   // 64*2048 bf16 (256 KB)
#define WS_PNAH  (2u << 20)   // 1024*2048 bf16 (4 MB)
#define WS_PNAL  (8u << 20)   // 1024*2048 bf16 (4 MB)
#define WS_PX    (14u << 20)  // 1024*64 f32 (256 KB)
#define WS_PD    (15u << 20)  // 1024*64 f32 (256 KB)

__device__ __forceinline__ float eluf(float v) {
  return v > 0.f ? v : __expf(v) - 1.f;
}

// ============ stage 1: prep (wredT, wmA fold) + per-row rcp rectangle ============
// blocks 0..1023    : one batch row each: pooled x/diff + antisym NDI rectangle (bf16 hi/lo)
// blocks 1024..1151 : wredT[sel][K][h] = colsum-rowsum of wm_di/wm_dd head h
// blocks 1152..1663 : wmA[h][e] = bf16(0.0625*(w[I,J]-w[J,I])) antisym fold
__global__ __launch_bounds__(256) void stage1_kernel(
    const float* __restrict__ x,
    const float* __restrict__ wm_di,
    const float* __restrict__ wm_ndi,
    const float* __restrict__ wm_dd,
    char* __restrict__ ws) {
  __shared__ float sm[64 * 65];  // rcp blocks use sm[0..255] as the x row
  const int t = threadIdx.x;

  if (blockIdx.x < 1024) {
    const int row = blockIdx.x;
    float* xs = sm;
    xs[t] = x[row * 256 + t];
    __syncthreads();
    // pooled x + telescoped pooled diff (wave 0 only)
    if (t < 64) {
      const int m = t, b4 = 4 * m;
      float* px_g = (float*)(ws + WS_PX);
      float* pd_g = (float*)(ws + WS_PD);
      px_g[row * 64 + m] = 0.25f * (xs[b4] + xs[b4 + 1] + xs[b4 + 2] + xs[b4 + 3]);
      const int i3 = min(b4 + 4, 255), i4 = min(b4 + 5, 255);
      const float smv = 0.2f * (xs[b4 + 1] + xs[b4 + 2] + xs[b4 + 3] + xs[i3] + xs[i4]);
      float prev = __shfl_up(smv, 1, 64);
      if (m == 0) prev = xs[0];
      pd_g[row * 64 + m] = 0.25f * (smv - prev);
    }
    // antisym rectangle: e -> (I=e>>5, J=(I+1+(e&31))&63), 8 entries/thread
    __hip_bfloat16* ph = (__hip_bfloat16*)(ws + WS_PNAH) + row * 2048;
    __hip_bfloat16* pl = (__hip_bfloat16*)(ws + WS_PNAL) + row * 2048;
#pragma unroll
    for (int i = 0; i < 8; ++i) {
      const int e = t + i * 256;
      const int I = e >> 5;
      const int J = (I + 1 + (e & 31)) & 63;
      const float4 xiv = *(const float4*)&xs[I << 2];
      const float4 xjv = *(const float4*)&xs[J << 2];
      const float xi_a[4] = {xiv.x, xiv.y, xiv.z, xiv.w};
      const float xj_a[4] = {xjv.x + 1e-5f, xjv.y + 1e-5f, xjv.z + 1e-5f, xjv.w + 1e-5f};
      const float xn_a[4] = {xjv.x, xjv.y, xjv.z, xjv.w};
      float s = 0.f;
#pragma unroll
      for (int a = 0; a < 4; ++a) {
#pragma unroll
        for (int c = 0; c < 4; ++c) {
          const float num = xn_a[c] - xi_a[a];
          const float den = xj_a[c] + xi_a[a];
          s += num * __builtin_amdgcn_rcpf(den);
        }
      }
      const __hip_bfloat16 hi = __float2bfloat16(s);
      const __hip_bfloat16 lo = __float2bfloat16(s - __bfloat162float(hi));
      ph[e] = hi;
      pl[e] = lo;
    }
  } else if (blockIdx.x < 1152) {
    const int b = blockIdx.x - 1024;
    const int sel = b >> 6, h = b & 63;
    const float* w = (sel ? wm_dd : wm_di) + h * 4096;
#pragma unroll 4
    for (int i = 0; i < 16; ++i) {
      const int e = i * 256 + t;
      sm[(e >> 6) * 65 + (e & 63)] = w[e];
    }
    __syncthreads();
    if (t < 64) {
      float cs = 0.f, rs = 0.f;
#pragma unroll 8
      for (int I = 0; I < 64; ++I) {
        cs += sm[I * 65 + t];
        rs += sm[t * 65 + I];
      }
      ((float*)(ws + WS_WREDT))[sel * 4096 + t * 64 + h] = cs - rs;
    }
  } else {
    const int gid = (blockIdx.x - 1152) * 256 + t;  // 0..131071
    const int h = gid >> 11, e = gid & 2047;
    const int I = e >> 5, tt = e & 31;
    const int J = (I + 1 + tt) & 63;
    float v = 0.f;
    if (!(tt == 31 && I >= 32)) {
      const float* w = wm_ndi + h * 4096;
      v = 0.0625f * (w[I * 64 + J] - w[J * 64 + I]);
    }
    ((__hip_bfloat16*)(ws + WS_WMA))[h * 2048 + e] = __float2bfloat16(v);
  }
}

// ============ stage 2: MFMA einsum + DI/DD proj + MLP tail ============
// grid 128, 512 threads, 8 rows per block (MFMA M padded to 16; pad rows discarded)
__global__ __launch_bounds__(512) void stage2_kernel(
    const char* __restrict__ ws,
    const float* __restrict__ b_di, const float* __restrict__ b_ndi,
    const float* __restrict__ b_dd,
    const float* __restrict__ fcw_di, const float* __restrict__ fcb_di,
    const float* __restrict__ fcw_ndi, const float* __restrict__ fcb_ndi,
    const float* __restrict__ fcw_dd, const float* __restrict__ fcb_dd,
    const float* __restrict__ fc1_w, const float* __restrict__ fc1_b,
    const float* __restrict__ fc2_w, const float* __restrict__ fc2_b,
    float* __restrict__ out) {
  // A tiles: [plane hi/lo][16 rows (8 real)][2048 + 8 pad] bf16 = 128.5 KB
  __shared__ short ldsA[2][16][2056];
  // overlay region (used only after the einsum barrier, inside ldsA's space):
  //   hpart: [8 kh][4 n][16 row][16 col] f32 = 8192
  //   hh   : [3][8][64] f32 = 1536
  //   emb  : [8][144]       = 1152
  //   f1v  : [8][48]        = 384
  float* ov = (float*)&ldsA[0][0][0];
  float* hp = ov;
  float* hh = ov + 8192;
  float* emb_s = ov + 9728;
  float* f1v_s = ov + 10880;

  const int t = threadIdx.x;
  const int b0 = blockIdx.x * 8;

  const __hip_bfloat16* __restrict__ wma = (const __hip_bfloat16*)(ws + WS_WMA);
  const __hip_bfloat16* __restrict__ ph = (const __hip_bfloat16*)(ws + WS_PNAH);
  const __hip_bfloat16* __restrict__ pl = (const __hip_bfloat16*)(ws + WS_PNAL);
  const float* __restrict__ wredT = (const float*)(ws + WS_WREDT);
  const float* __restrict__ px_g = (const float*)(ws + WS_PX);
  const float* __restrict__ pd_g = (const float*)(ws + WS_PD);

  // ---- stage A rows (8 real rows x 2048, hi & lo planes) into LDS ----
#pragma unroll
  for (int p = 0; p < 2; ++p) {
    const __hip_bfloat16* src = p ? pl : ph;
#pragma unroll
    for (int i = 0; i < 4; ++i) {
      const int gi = i * 512 + t;         // 0..2047 chunks of 8 bf16
      const int row = gi >> 8, c8 = gi & 255;
      const short8 v = *(const short8*)(src + (b0 + row) * 2048 + c8 * 8);
      *(short8*)&ldsA[p][row][c8 * 8] = v;
    }
  }
  __syncthreads();

  // ---- einsum via MFMA: wave w owns K-eighth (256 elems), all 4 N-tiles ----
  const int wv = t >> 6, lane = t & 63;
  const int arow = lane & 15, kb = lane >> 4;
  floatx4 acc0 = {0.f, 0.f, 0.f, 0.f}, acc1 = {0.f, 0.f, 0.f, 0.f};
  floatx4 acc2 = {0.f, 0.f, 0.f, 0.f}, acc3 = {0.f, 0.f, 0.f, 0.f};
  {
    const int kbase = wv * 256;
#pragma unroll
    for (int s = 0; s < 8; ++s) {
      const int ke = kbase + s * 32 + kb * 8;
      const short8 ah = *(const short8*)&ldsA[0][arow][ke];
      const short8 al = *(const short8*)&ldsA[1][arow][ke];
      const short8 bv0 = *(const short8*)(wma + (0 + arow) * 2048 + ke);
      const short8 bv1 = *(const short8*)(wma + (16 + arow) * 2048 + ke);
      const short8 bv2 = *(const short8*)(wma + (32 + arow) * 2048 + ke);
      const short8 bv3 = *(const short8*)(wma + (48 + arow) * 2048 + ke);
      acc0 = __builtin_amdgcn_mfma_f32_16x16x32_bf16(ah, bv0, acc0, 0, 0, 0);
      acc0 = __builtin_amdgcn_mfma_f32_16x16x32_bf16(al, bv0, acc0, 0, 0, 0);
      acc1 = __builtin_amdgcn_mfma_f32_16x16x32_bf16(ah, bv1, acc1, 0, 0, 0);
      acc1 = __builtin_amdgcn_mfma_f32_16x16x32_bf16(al, bv1, acc1, 0, 0, 0);
      acc2 = __builtin_amdgcn_mfma_f32_16x16x32_bf16(ah, bv2, acc2, 0, 0, 0);
      acc2 = __builtin_amdgcn_mfma_f32_16x16x32_bf16(al, bv2, acc2, 0, 0, 0);
      acc3 = __builtin_amdgcn_mfma_f32_16x16x32_bf16(ah, bv3, acc3, 0, 0, 0);
      acc3 = __builtin_amdgcn_mfma_f32_16x16x32_bf16(al, bv3, acc3, 0, 0, 0);
    }
  }
  __syncthreads();  // all einsum LDS reads done; ldsA space becomes overlay

  // ---- write per-wave partials: C/D layout col=lane&15, row=(lane>>4)*4+reg (m89) ----
  {
    const int orow = (lane >> 4) * 4, ocol = lane & 15;
#pragma unroll
    for (int r = 0; r < 4; ++r) {
      hp[((wv * 4 + 0) * 16 + orow + r) * 16 + ocol] = acc0[r];
      hp[((wv * 4 + 1) * 16 + orow + r) * 16 + ocol] = acc1[r];
      hp[((wv * 4 + 2) * 16 + orow + r) * 16 + ocol] = acc2[r];
      hp[((wv * 4 + 3) * 16 + orow + r) * 16 + ocol] = acc3[r];
    }
  }
  __syncthreads();

  // ---- combine K-eighths (NDI heads) + DI/DD separable projections ----
  {
    const int row = t >> 6, h = t & 63;  // 8 real rows x 64
    const int n = h >> 4, c = h & 15;
    float v = b_ndi[h];
#pragma unroll
    for (int kh = 0; kh < 8; ++kh) v += hp[((kh * 4 + n) * 16 + row) * 16 + c];
    hh[1 * 512 + row * 64 + h] = eluf(v);

    float adi = b_di[h], add_ = b_dd[h];
    const float* pxr = px_g + (b0 + row) * 64;
    const float* pdr = pd_g + (b0 + row) * 64;
#pragma unroll 8
    for (int K = 0; K < 64; ++K) {
      adi += pxr[K] * wredT[K * 64 + h];
      add_ += pdr[K] * wredT[4096 + K * 64 + h];
    }
    hh[0 * 512 + row * 64 + h] = eluf(adi);
    hh[2 * 512 + row * 64 + h] = eluf(add_);
  }
  __syncthreads();

  // ---- per-picker fc: HEAD(64) -> EMB(48), concatenated emb[8][144] ----
  for (int idx = t; idx < 8 * 144; idx += 512) {
    const int r = idx / 144;
    const int k = idx - r * 144;
    const int pick = k / 48;
    const int e = k - pick * 48;
    const float* __restrict__ fw = (pick == 0) ? fcw_di : (pick == 1) ? fcw_ndi : fcw_dd;
    const float* __restrict__ fb = (pick == 0) ? fcb_di : (pick == 1) ? fcb_ndi : fcb_dd;
    float a = fb[e];
#pragma unroll 8
    for (int hq = 0; hq < 64; ++hq) a += hh[pick * 512 + r * 64 + hq] * fw[e * 64 + hq];
    emb_s[idx] = eluf(a);
  }
  __syncthreads();

  // ---- fc1: 144 -> 48, elu ----
  if (t < 8 * 48) {
    const int r = t / 48, o = t - (t / 48) * 48;
    float a = fc1_b[o];
#pragma unroll 8
    for (int k = 0; k < 144; ++k) a += emb_s[r * 144 + k] * fc1_w[o * 144 + k];
    f1v_s[t] = eluf(a);
  }
  __syncthreads();

  // ---- fc2: 48 -> 20 ----
  if (t < 8 * 20) {
    const int r = t / 20, o = t - (t / 20) * 20;
    float a = fc2_b[o];
#pragma unroll
    for (int j = 0; j < 48; ++j) a += f1v_s[r * 48 + j] * fc2_w[o * 48 + j];
    out[(b0 + r) * 20 + o] = a;
  }
}

extern "C" void kernel_launch(void* const* d_in, const int* in_sizes, int n_in,
                              void* d_out, int out_size, void* d_ws, size_t ws_size,
                              hipStream_t stream) {
  const float* x       = (const float*)d_in[0];
  const float* wm_di   = (const float*)d_in[1];
  const float* b_di    = (const float*)d_in[2];
  const float* fcw_di  = (const float*)d_in[3];
  const float* fcb_di  = (const float*)d_in[4];
  const float* wm_ndi  = (const float*)d_in[5];
  const float* b_ndi   = (const float*)d_in[6];
  const float* fcw_ndi = (const float*)d_in[7];
  const float* fcb_ndi = (const float*)d_in[8];
  const float* wm_dd   = (const float*)d_in[9];
  const float* b_dd    = (const float*)d_in[10];
  const float* fcw_dd  = (const float*)d_in[11];
  const float* fcb_dd  = (const float*)d_in[12];
  const float* fc1_w   = (const float*)d_in[13];
  const float* fc1_b   = (const float*)d_in[14];
  const float* fc2_w   = (const float*)d_in[15];
  const float* fc2_b   = (const float*)d_in[16];
  float* out = (float*)d_out;
  char* ws = (char*)d_ws;

  stage1_kernel<<<1664, 256, 0, stream>>>(x, wm_di, wm_ndi, wm_dd, ws);
  stage2_kernel<<<128, 512, 0, stream>>>(
      ws, b_di, b_ndi, b_dd,
      fcw_di, fcb_di, fcw_ndi, fcb_ndi, fcw_dd, fcb_dd,
      fc1_w, fc1_b, fc2_w, fc2_b, out);
}

// Round 6
// 27.952 us; speedup vs baseline: 1.5049x; 1.5049x over previous
//
#include <hip/hip_runtime.h>
#include <hip/hip_bf16.h>
#include <math.h>

typedef __attribute__((ext_vector_type(8))) short short8;
typedef __attribute__((ext_vector_type(4))) float floatx4;

// ---- workspace layout ----
#define WS_WREDT 0u          // 8192 f32 (32 KB)
#define WS_WMAT  (1u << 20)  // 4*64*64*8 bf16 = 256 KB, B-fragment-swizzled

__device__ __forceinline__ float eluf(float v) {
  return v > 0.f ? v : __expf(v) - 1.f;
}

__device__ __forceinline__ unsigned short f2bf(float f) {
  __hip_bfloat16 h = __float2bfloat16(f);
  return *reinterpret_cast<unsigned short*>(&h);
}

// ============ prep ============
// blocks 0..127  : wredT[sel][K][h] = colsum-rowsum of wm_di/wm_dd head h (LDS transpose)
// blocks 128..639: wmaT in MFMA-B-fragment layout: element gid = ((n*64+kstep)*64+lane)*8+j
//                  holds bf16(0.0625*(w[h,I,J]-w[h,J,I])) with h = n*16+(lane&15),
//                  k = kstep*32+(lane>>4)*8+j, rectangle map I=k>>5, J=(I+1+(k&31))&63,
//                  zeroed on duplicate columns (k&31==31 && I>=32).
__global__ __launch_bounds__(256) void prep_kernel(
    const float* __restrict__ wm_di,
    const float* __restrict__ wm_ndi,
    const float* __restrict__ wm_dd,
    char* __restrict__ ws) {
  __shared__ float sm[64 * 65];
  const int t = threadIdx.x;
  if (blockIdx.x < 128) {
    const int sel = blockIdx.x >> 6, h = blockIdx.x & 63;
    const float* w = (sel ? wm_dd : wm_di) + h * 4096;
#pragma unroll 4
    for (int i = 0; i < 16; ++i) {
      const int e = i * 256 + t;
      sm[(e >> 6) * 65 + (e & 63)] = w[e];
    }
    __syncthreads();
    if (t < 64) {
      float cs = 0.f, rs = 0.f;
#pragma unroll 8
      for (int I = 0; I < 64; ++I) {
        cs += sm[I * 65 + t];
        rs += sm[t * 65 + I];
      }
      ((float*)(ws + WS_WREDT))[sel * 4096 + t * 64 + h] = cs - rs;
    }
  } else {
    const int gid = (blockIdx.x - 128) * 256 + t;  // 0..131071
    const int lane = (gid >> 3) & 63, kstep = (gid >> 9) & 63, n = gid >> 15;
    const int h = n * 16 + (lane & 15);
    const int k = kstep * 32 + ((lane >> 4) << 3) + (gid & 7);
    const int I = k >> 5, tt = k & 31;
    const int J = (I + 1 + tt) & 63;
    float v = 0.f;
    if (!(tt == 31 && I >= 32))
      v = 0.0625f * (wm_ndi[h * 4096 + I * 64 + J] - wm_ndi[h * 4096 + J * 64 + I]);
    ((__hip_bfloat16*)(ws + WS_WMAT))[gid] = __float2bfloat16(v);
  }
}

// ============ fused: rcp rectangle -> in-LDS MFMA einsum -> MLP tail ============
// grid 512, 1024 threads (16 waves), 2 batch rows per block
__global__ __launch_bounds__(1024, 8) void fused_kernel(
    const float* __restrict__ x,
    const float* __restrict__ b_di, const float* __restrict__ b_ndi,
    const float* __restrict__ b_dd,
    const float* __restrict__ fcw_di, const float* __restrict__ fcb_di,
    const float* __restrict__ fcw_ndi, const float* __restrict__ fcb_ndi,
    const float* __restrict__ fcw_dd, const float* __restrict__ fcb_dd,
    const float* __restrict__ fc1_w, const float* __restrict__ fc1_b,
    const float* __restrict__ fc2_w, const float* __restrict__ fc2_b,
    const char* __restrict__ ws,
    float* __restrict__ out) {
  __shared__ float xs[2][256];
  __shared__ __align__(16) unsigned short ldsA[2][2][2048];  // [plane hi/lo][row][k] bf16
  __shared__ float pxs[2][64], pds[2][64];
  __shared__ float hp[16][4][2][16];  // [kh][n][row][col] einsum partials
  __shared__ float hh[3][2][64];
  __shared__ float emb_s[2][144];
  __shared__ float f1v_s[2][48];

  const int t = threadIdx.x;
  const int b0 = blockIdx.x * 2;
  const float* __restrict__ wredT = (const float*)(ws + WS_WREDT);
  const short* __restrict__ wmaT = (const short*)(ws + WS_WMAT);

  if (t < 512) xs[t >> 8][t & 255] = x[(b0 + (t >> 8)) * 256 + (t & 255)];
  __syncthreads();

  // ---- pooled x + telescoped pooled diff (2 waves) ----
  if (t < 128) {
    const int r = t >> 6, m = t & 63;
    const float* __restrict__ xr = xs[r];
    const int b4 = 4 * m;
    pxs[r][m] = 0.25f * (xr[b4] + xr[b4 + 1] + xr[b4 + 2] + xr[b4 + 3]);
    const int i3 = min(b4 + 4, 255), i4 = min(b4 + 5, 255);
    const float smv = 0.2f * (xr[b4 + 1] + xr[b4 + 2] + xr[b4 + 3] + xr[i3] + xr[i4]);
    float prev = __shfl_up(smv, 1, 64);
    if (m == 0) prev = xr[0];
    pds[r][m] = 0.25f * (smv - prev);
  }

  // ---- antisym rcp rectangle -> LDS bf16 hi/lo: 4096 entries, 4/thread ----
#pragma unroll
  for (int i = 0; i < 4; ++i) {
    const int cc = t + i * 1024;
    const int r = cc >> 11, e = cc & 2047;
    const int I = e >> 5;
    const int J = (I + 1 + (e & 31)) & 63;
    const float4 xiv = *(const float4*)&xs[r][I << 2];
    const float4 xjv = *(const float4*)&xs[r][J << 2];
    const float xi_a[4] = {xiv.x, xiv.y, xiv.z, xiv.w};
    const float xj_a[4] = {xjv.x + 1e-5f, xjv.y + 1e-5f, xjv.z + 1e-5f, xjv.w + 1e-5f};
    const float xn_a[4] = {xjv.x, xjv.y, xjv.z, xjv.w};
    float s = 0.f;
#pragma unroll
    for (int a = 0; a < 4; ++a) {
#pragma unroll
      for (int c = 0; c < 4; ++c) {
        const float num = xn_a[c] - xi_a[a];
        const float den = xj_a[c] + xi_a[a];
        s += num * __builtin_amdgcn_rcpf(den);
      }
    }
    const unsigned short hi = f2bf(s);
    union { unsigned int u; float f; } hv; hv.u = ((unsigned int)hi) << 16;
    ldsA[0][r][e] = hi;
    ldsA[1][r][e] = f2bf(s - hv.f);
  }
  __syncthreads();

  // ---- MFMA einsum: wave kh owns K-slice of 128; n-outer to keep regs low ----
  {
    const int kh = t >> 6, lane = t & 63;
    const int arow = lane & 1;                       // logical row (lane&15) -> physical &1
    const int kofs = kh * 128 + ((lane >> 4) << 3);  // element offset within row
#pragma unroll
    for (int n = 0; n < 4; ++n) {
      floatx4 acc = {0.f, 0.f, 0.f, 0.f};
#pragma unroll
      for (int s = 0; s < 4; ++s) {
        const int kk = kofs + s * 32;
        const short8 ah = *(const short8*)&ldsA[0][arow][kk];
        const short8 al = *(const short8*)&ldsA[1][arow][kk];
        const int kstep = kh * 4 + s;
        const short8 bv = *(const short8*)(wmaT + (((n * 64 + kstep) * 64 + lane) << 3));
        acc = __builtin_amdgcn_mfma_f32_16x16x32_bf16(ah, bv, acc, 0, 0, 0);
        acc = __builtin_amdgcn_mfma_f32_16x16x32_bf16(al, bv, acc, 0, 0, 0);
      }
      // C/D layout (m89): col=lane&15, row=(lane>>4)*4+reg -> rows 0,1 live in lanes 0..15
      if (lane < 16) {
        hp[kh][n][0][lane] = acc[0];
        hp[kh][n][1][lane] = acc[1];
      }
    }
  }

  // ---- DI/DD separable projections (same barrier interval; reads pxs/pds + wredT) ----
  if (t < 128) {
    const int r = t >> 6, h = t & 63;
    float adi = b_di[h], add_ = b_dd[h];
#pragma unroll 8
    for (int K = 0; K < 64; ++K) {
      adi += pxs[r][K] * wredT[K * 64 + h];
      add_ += pds[r][K] * wredT[4096 + K * 64 + h];
    }
    hh[0][r][h] = eluf(adi);
    hh[2][r][h] = eluf(add_);
  }
  __syncthreads();

  // ---- combine K-slice partials -> NDI heads ----
  if (t < 128) {
    const int row = t >> 6, h = t & 63;
    const int n = h >> 4, c = h & 15;
    float v = b_ndi[h];
#pragma unroll
    for (int kh = 0; kh < 16; ++kh) v += hp[kh][n][row][c];
    hh[1][row][h] = eluf(v);
  }
  __syncthreads();

  // ---- per-picker fc: HEAD(64) -> EMB(48), concatenated emb[2][144] ----
  if (t < 2 * 144) {
    const int r = t / 144;
    const int k = t - r * 144;
    const int pick = k / 48;
    const int e = k - pick * 48;
    const float* __restrict__ fw = (pick == 0) ? fcw_di : (pick == 1) ? fcw_ndi : fcw_dd;
    const float* __restrict__ fb = (pick == 0) ? fcb_di : (pick == 1) ? fcb_ndi : fcb_dd;
    float a = fb[e];
#pragma unroll 8
    for (int hq = 0; hq < 64; ++hq) a += hh[pick][r][hq] * fw[e * 64 + hq];
    emb_s[r][k] = eluf(a);
  }
  __syncthreads();

  // ---- fc1: 144 -> 48, elu ----
  if (t < 2 * 48) {
    const int r = t / 48, o = t - (t / 48) * 48;
    float a = fc1_b[o];
#pragma unroll 8
    for (int k = 0; k < 144; ++k) a += emb_s[r][k] * fc1_w[o * 144 + k];
    f1v_s[r][o] = eluf(a);
  }
  __syncthreads();

  // ---- fc2: 48 -> 20 ----
  if (t < 2 * 20) {
    const int r = t / 20, o = t - (t / 20) * 20;
    float a = fc2_b[o];
#pragma unroll
    for (int j = 0; j < 48; ++j) a += f1v_s[r][j] * fc2_w[o * 48 + j];
    out[(b0 + r) * 20 + o] = a;
  }
}

extern "C" void kernel_launch(void* const* d_in, const int* in_sizes, int n_in,
                              void* d_out, int out_size, void* d_ws, size_t ws_size,
                              hipStream_t stream) {
  const float* x       = (const float*)d_in[0];
  const float* wm_di   = (const float*)d_in[1];
  const float* b_di    = (const float*)d_in[2];
  const float* fcw_di  = (const float*)d_in[3];
  const float* fcb_di  = (const float*)d_in[4];
  const float* wm_ndi  = (const float*)d_in[5];
  const float* b_ndi   = (const float*)d_in[6];
  const float* fcw_ndi = (const float*)d_in[7];
  const float* fcb_ndi = (const float*)d_in[8];
  const float* wm_dd   = (const float*)d_in[9];
  const float* b_dd    = (const float*)d_in[10];
  const float* fcw_dd  = (const float*)d_in[11];
  const float* fcb_dd  = (const float*)d_in[12];
  const float* fc1_w   = (const float*)d_in[13];
  const float* fc1_b   = (const float*)d_in[14];
  const float* fc2_w   = (const float*)d_in[15];
  const float* fc2_b   = (const float*)d_in[16];
  float* out = (float*)d_out;
  char* ws = (char*)d_ws;

  prep_kernel<<<640, 256, 0, stream>>>(wm_di, wm_ndi, wm_dd, ws);
  fused_kernel<<<512, 1024, 0, stream>>>(
      x, b_di, b_ndi, b_dd,
      fcw_di, fcb_di, fcw_ndi, fcb_ndi, fcw_dd, fcb_dd,
      fc1_w, fc1_b, fc2_w, fc2_b, ws, out);
}

// Round 7
// 27.043 us; speedup vs baseline: 1.5555x; 1.0336x over previous
//
#include <hip/hip_runtime.h>
#include <hip/hip_bf16.h>
#include <math.h>

typedef __attribute__((ext_vector_type(8))) short short8;
typedef __attribute__((ext_vector_type(4))) float floatx4;

// ---- workspace layout ----
#define WS_WREDT 0u          // 8192 f32 (32 KB)
#define WS_WMAT  (1u << 20)  // 4*64*64*8 bf16 = 256 KB, B-fragment-swizzled

__device__ __forceinline__ float eluf(float v) {
  return v > 0.f ? v : __expf(v) - 1.f;
}

__device__ __forceinline__ unsigned short f2bf(float f) {
  __hip_bfloat16 h = __float2bfloat16(f);
  return *reinterpret_cast<unsigned short*>(&h);
}

// ============ prep ============
// blocks 0..127: wredT[sel][K][h] = colsum-rowsum of wm_di/wm_dd head h (LDS transpose)
// blocks 128..191: per-head wmaT fold, LDS-staged:
//   wmaT element gid = ((n*64+kstep)*64+lane)*8+j holds
//   bf16(0.0625*(w[h,I,J]-w[h,J,I])), h = n*16+(lane&15), k = kstep*32+(lane>>4)*8+j,
//   I = k>>5, J = (I+1+(k&31))&63, zeroed on duplicates (k&31==31 && I>=32).
__global__ __launch_bounds__(256) void prep_kernel(
    const float* __restrict__ wm_di,
    const float* __restrict__ wm_ndi,
    const float* __restrict__ wm_dd,
    char* __restrict__ ws) {
  __shared__ float sm[64 * 65];
  const int t = threadIdx.x;
  if (blockIdx.x < 128) {
    const int sel = blockIdx.x >> 6, h = blockIdx.x & 63;
    const float* w = (sel ? wm_dd : wm_di) + h * 4096;
#pragma unroll 4
    for (int i = 0; i < 16; ++i) {
      const int e = i * 256 + t;
      sm[(e >> 6) * 65 + (e & 63)] = w[e];
    }
    __syncthreads();
    if (t < 64) {
      float cs = 0.f, rs = 0.f;
#pragma unroll 8
      for (int I = 0; I < 64; ++I) {
        cs += sm[I * 65 + t];
        rs += sm[t * 65 + I];
      }
      ((float*)(ws + WS_WREDT))[sel * 4096 + t * 64 + h] = cs - rs;
    }
  } else {
    const int h = blockIdx.x - 128;  // 0..63
    const float* w = wm_ndi + h * 4096;
#pragma unroll 4
    for (int i = 0; i < 16; ++i) {
      const int e = i * 256 + t;
      sm[(e >> 6) * 65 + (e & 63)] = w[e];
    }
    __syncthreads();
    const int kstep = t >> 2, kc = t & 3;
    const int lane = kc * 16 + (h & 15);
    const int n = h >> 4;
    short8 sv;
#pragma unroll
    for (int j = 0; j < 8; ++j) {
      const int k = kstep * 32 + kc * 8 + j;
      const int I = k >> 5, tt = k & 31;
      const int J = (I + 1 + tt) & 63;
      float v = 0.f;
      if (!(tt == 31 && I >= 32))
        v = 0.0625f * (sm[I * 65 + J] - sm[J * 65 + I]);
      sv[j] = (short)f2bf(v);
    }
    *(short8*)((__hip_bfloat16*)(ws + WS_WMAT) + (((n * 64 + kstep) * 64 + lane) << 3)) = sv;
  }
}

// ============ fused: paired-rcp rectangle -> in-LDS MFMA einsum -> MLP tail ============
// grid 512, 1024 threads (16 waves), 2 batch rows per block
__global__ __launch_bounds__(1024, 8) void fused_kernel(
    const float* __restrict__ x,
    const float* __restrict__ b_di, const float* __restrict__ b_ndi,
    const float* __restrict__ b_dd,
    const float* __restrict__ fcw_di, const float* __restrict__ fcb_di,
    const float* __restrict__ fcw_ndi, const float* __restrict__ fcb_ndi,
    const float* __restrict__ fcw_dd, const float* __restrict__ fcb_dd,
    const float* __restrict__ fc1_w, const float* __restrict__ fc1_b,
    const float* __restrict__ fc2_w, const float* __restrict__ fc2_b,
    const char* __restrict__ ws,
    float* __restrict__ out) {
  __shared__ float xs[2][256];
  __shared__ __align__(16) unsigned short ldsA[2][2][2048];  // [plane hi/lo][row][k] bf16
  __shared__ float pxs[2][64], pds[2][64];
  __shared__ float hp[16][4][2][16];  // [kh][n][row][col] einsum partials
  __shared__ float hh[3][2][64];
  __shared__ float emb_s[2][144];
  __shared__ float f1v_s[2][48];

  const int t = threadIdx.x;
  const int b0 = blockIdx.x * 2;
  const float* __restrict__ wredT = (const float*)(ws + WS_WREDT);
  const short* __restrict__ wmaT = (const short*)(ws + WS_WMAT);

  if (t < 512) xs[t >> 8][t & 255] = x[(b0 + (t >> 8)) * 256 + (t & 255)];
  __syncthreads();

  // ---- pooled x + telescoped pooled diff (2 waves) ----
  if (t < 128) {
    const int r = t >> 6, m = t & 63;
    const float* __restrict__ xr = xs[r];
    const int b4 = 4 * m;
    pxs[r][m] = 0.25f * (xr[b4] + xr[b4 + 1] + xr[b4 + 2] + xr[b4 + 3]);
    const int i3 = min(b4 + 4, 255), i4 = min(b4 + 5, 255);
    const float smv = 0.2f * (xr[b4 + 1] + xr[b4 + 2] + xr[b4 + 3] + xr[i3] + xr[i4]);
    float prev = __shfl_up(smv, 1, 64);
    if (m == 0) prev = xr[0];
    pds[r][m] = 0.25f * (smv - prev);
  }

  // ---- antisym rcp rectangle -> LDS bf16 hi/lo: 4096 entries, 4/thread ----
  // paired fractions (exact algebra):
  //   (d0-y)/(d0+y+e) + (d1-y)/(d1+y+e)
  //     = [2*d0*d1 + (d0+d1)*e - 2*y*(y+e)] / [(d0+y+e)*(d1+y+e)]
  // -> 8 rcp per entry instead of 16.
#pragma unroll 1
  for (int i = 0; i < 4; ++i) {
    const int cc = t + i * 1024;
    const int r = cc >> 11, e = cc & 2047;
    const int I = e >> 5;
    const int J = (I + 1 + (e & 31)) & 63;
    const float4 xiv = *(const float4*)&xs[r][I << 2];
    const float4 xjv = *(const float4*)&xs[r][J << 2];
    const float P01 = 2.f * xjv.x * xjv.y + (xjv.x + xjv.y) * 1e-5f;
    const float P23 = 2.f * xjv.z * xjv.w + (xjv.z + xjv.w) * 1e-5f;
    const float ya[4] = {xiv.x, xiv.y, xiv.z, xiv.w};
    float s = 0.f;
#pragma unroll
    for (int a = 0; a < 4; ++a) {
      const float y = ya[a];
      const float u = y + 1e-5f;
      const float G = 2.f * y * u;
      const float D0 = (xjv.x + u) * (xjv.y + u);
      const float D1 = (xjv.z + u) * (xjv.w + u);
      s += (P01 - G) * __builtin_amdgcn_rcpf(D0);
      s += (P23 - G) * __builtin_amdgcn_rcpf(D1);
    }
    const unsigned short hi = f2bf(s);
    union { unsigned int uu; float f; } hv; hv.uu = ((unsigned int)hi) << 16;
    ldsA[0][r][e] = hi;
    ldsA[1][r][e] = f2bf(s - hv.f);
  }
  __syncthreads();

  // ---- MFMA einsum: wave kh owns K-slice of 128; n-outer to keep regs low ----
  {
    const int kh = t >> 6, lane = t & 63;
    const int arow = lane & 1;                       // logical row (lane&15) -> physical &1
    const int kofs = kh * 128 + ((lane >> 4) << 3);  // element offset within row
#pragma unroll
    for (int n = 0; n < 4; ++n) {
      floatx4 acc = {0.f, 0.f, 0.f, 0.f};
#pragma unroll
      for (int s = 0; s < 4; ++s) {
        const int kk = kofs + s * 32;
        const short8 ah = *(const short8*)&ldsA[0][arow][kk];
        const short8 al = *(const short8*)&ldsA[1][arow][kk];
        const int kstep = kh * 4 + s;
        const short8 bv = *(const short8*)(wmaT + (((n * 64 + kstep) * 64 + lane) << 3));
        acc = __builtin_amdgcn_mfma_f32_16x16x32_bf16(ah, bv, acc, 0, 0, 0);
        acc = __builtin_amdgcn_mfma_f32_16x16x32_bf16(al, bv, acc, 0, 0, 0);
      }
      // C/D layout (m89): col=lane&15, row=(lane>>4)*4+reg -> rows 0,1 live in lanes 0..15
      if (lane < 16) {
        hp[kh][n][0][lane] = acc[0];
        hp[kh][n][1][lane] = acc[1];
      }
    }
  }

  // ---- DI/DD separable projections (same barrier interval; reads pxs/pds + wredT) ----
  if (t < 128) {
    const int r = t >> 6, h = t & 63;
    float adi = b_di[h], add_ = b_dd[h];
#pragma unroll 8
    for (int K = 0; K < 64; ++K) {
      adi += pxs[r][K] * wredT[K * 64 + h];
      add_ += pds[r][K] * wredT[4096 + K * 64 + h];
    }
    hh[0][r][h] = eluf(adi);
    hh[2][r][h] = eluf(add_);
  }
  __syncthreads();

  // ---- combine K-slice partials -> NDI heads ----
  if (t < 128) {
    const int row = t >> 6, h = t & 63;
    const int n = h >> 4, c = h & 15;
    float v = b_ndi[h];
#pragma unroll
    for (int kh = 0; kh < 16; ++kh) v += hp[kh][n][row][c];
    hh[1][row][h] = eluf(v);
  }
  __syncthreads();

  // ---- per-picker fc: HEAD(64) -> EMB(48), concatenated emb[2][144] ----
  if (t < 2 * 144) {
    const int r = t / 144;
    const int k = t - r * 144;
    const int pick = k / 48;
    const int e = k - pick * 48;
    const float* __restrict__ fw = (pick == 0) ? fcw_di : (pick == 1) ? fcw_ndi : fcw_dd;
    const float* __restrict__ fb = (pick == 0) ? fcb_di : (pick == 1) ? fcb_ndi : fcb_dd;
    float a = fb[e];
#pragma unroll 8
    for (int hq = 0; hq < 64; ++hq) a += hh[pick][r][hq] * fw[e * 64 + hq];
    emb_s[r][k] = eluf(a);
  }
  __syncthreads();

  // ---- fc1: 144 -> 48, elu ----
  if (t < 2 * 48) {
    const int r = t / 48, o = t - (t / 48) * 48;
    float a = fc1_b[o];
#pragma unroll 8
    for (int k = 0; k < 144; ++k) a += emb_s[r][k] * fc1_w[o * 144 + k];
    f1v_s[r][o] = eluf(a);
  }
  __syncthreads();

  // ---- fc2: 48 -> 20 ----
  if (t < 2 * 20) {
    const int r = t / 20, o = t - (t / 20) * 20;
    float a = fc2_b[o];
#pragma unroll
    for (int j = 0; j < 48; ++j) a += f1v_s[r][j] * fc2_w[o * 48 + j];
    out[(b0 + r) * 20 + o] = a;
  }
}

extern "C" void kernel_launch(void* const* d_in, const int* in_sizes, int n_in,
                              void* d_out, int out_size, void* d_ws, size_t ws_size,
                              hipStream_t stream) {
  const float* x       = (const float*)d_in[0];
  const float* wm_di   = (const float*)d_in[1];
  const float* b_di    = (const float*)d_in[2];
  const float* fcw_di  = (const float*)d_in[3];
  const float* fcb_di  = (const float*)d_in[4];
  const float* wm_ndi  = (const float*)d_in[5];
  const float* b_ndi   = (const float*)d_in[6];
  const float* fcw_ndi = (const float*)d_in[7];
  const float* fcb_ndi = (const float*)d_in[8];
  const float* wm_dd   = (const float*)d_in[9];
  const float* b_dd    = (const float*)d_in[10];
  const float* fcw_dd  = (const float*)d_in[11];
  const float* fcb_dd  = (const float*)d_in[12];
  const float* fc1_w   = (const float*)d_in[13];
  const float* fc1_b   = (const float*)d_in[14];
  const float* fc2_w   = (const float*)d_in[15];
  const float* fc2_b   = (const float*)d_in[16];
  float* out = (float*)d_out;
  char* ws = (char*)d_ws;

  prep_kernel<<<192, 256, 0, stream>>>(wm_di, wm_ndi, wm_dd, ws);
  fused_kernel<<<512, 1024, 0, stream>>>(
      x, b_di, b_ndi, b_dd,
      fcw_di, fcb_di, fcw_ndi, fcb_ndi, fcw_dd, fcb_dd,
      fc1_w, fc1_b, fc2_w, fc2_b, ws, out);
}